// Round 11
// baseline (125.249 us; speedup 1.0000x reference)
//
#include <hip/hip_runtime.h>

#define H 4
#define Nq 4096
#define SEG 8
#define NKT ((Nq / SEG) / 64)
#define LOG2E 1.44269504088896340736f

typedef unsigned short ushortT;
typedef __attribute__((ext_vector_type(4))) short short4T;
typedef __attribute__((ext_vector_type(8))) short short8;
typedef __attribute__((ext_vector_type(4))) float floatx4;

// raw pipeline primitives (R4/R7/R8/R9-verified)
#define WAIT_VM0() asm volatile("s_waitcnt vmcnt(0)" ::: "memory")
#define BARRIER()  asm volatile("s_barrier" ::: "memory")

// round-half-up f32 -> bf16 (inputs finite)
static __device__ __forceinline__ ushortT f2bf(float x) {
    unsigned int u = __builtin_bit_cast(unsigned int, x);
    return (ushortT)((u + 0x8000u) >> 16);
}
static __device__ __forceinline__ float bf2f(ushortT h) {
    return __builtin_bit_cast(float, (unsigned int)h << 16);
}

// async global->LDS: PER-LANE global address -> LDS uniform base + lane*16.
static __device__ __forceinline__ void gld16(const void* g, void* l) {
    __builtin_amdgcn_global_load_lds(
        reinterpret_cast<const __attribute__((address_space(1))) unsigned int*>(
            reinterpret_cast<unsigned long long>(g)),
        reinterpret_cast<__attribute__((address_space(3))) unsigned int*>(
            static_cast<unsigned int>(reinterpret_cast<unsigned long long>(l))),
        16, 0, 0);
}

// ---------------------------------------------------------------------------
// Kernel 1 (unchanged from R9/R10): QKV projection + stack + vec-activation;
//   z==6 builds hi/lo split EXTENDED pos features (16 bf16 slots per side) so
//   attn computes the full logit (QK + distance bias, incl. log2e) in MFMA.
//   V stored PERMUTED (32-key groups, slot quad*8+hi*4+r) for b128 PV frags.
// ---------------------------------------------------------------------------
__global__ __launch_bounds__(256) void qkv_kernel(
    const float* __restrict__ ax, const float* __restrict__ vx,
    const float* __restrict__ pos_q, const float* __restrict__ pos_k,
    const float* __restrict__ Waq, const float* __restrict__ Wvq,
    const float* __restrict__ Wak, const float* __restrict__ Wvk,
    const float* __restrict__ Wav, const float* __restrict__ Wvv,
    ushortT* __restrict__ Qg, ushortT* __restrict__ Kg, ushortT* __restrict__ Vtg,
    ushortT* __restrict__ Qe, ushortT* __restrict__ Ke)
{
    const int h = blockIdx.y;
    const int n = blockIdx.x * 256 + threadIdx.x;

    if (blockIdx.z == 6) {      // extended pos-feature branch (block-uniform)
        const float c = LOG2E / (float)(1 << (2 * h));
        const ushortT one = 0x3F80;
        {   // Q side
            const float* p = pos_q + ((size_t)h * Nq + n) * 3;
            const float x = 2.f*c*p[0], y = 2.f*c*p[1], z = 2.f*c*p[2];
            const float wq = -c * (p[0]*p[0] + p[1]*p[1] + p[2]*p[2]);
            const ushortT xh = f2bf(x), yh = f2bf(y), zh = f2bf(z), wh = f2bf(wq);
            const ushortT xl = f2bf(x - bf2f(xh)), yl = f2bf(y - bf2f(yh));
            const ushortT zl = f2bf(z - bf2f(zh)), wl = f2bf(wq - bf2f(wh));
            __attribute__((aligned(16))) ushortT qe[16] =
                { xh, xl, xh,  yh, yl, yh,  zh, zl, zh,
                  wh, wl, one, one, xl, yl, zl };
            ushortT* dst = Qe + ((size_t)h * Nq + n) * 16;
            ((short8*)dst)[0] = ((const short8*)qe)[0];
            ((short8*)dst)[1] = ((const short8*)qe)[1];
        }
        {   // K side
            const float* p = pos_k + ((size_t)h * Nq + n) * 3;
            const float x = p[0], y = p[1], z = p[2];
            const float sk = -c * (x*x + y*y + z*z);
            const ushortT xh = f2bf(x), yh = f2bf(y), zh = f2bf(z), sh = f2bf(sk);
            const ushortT xl = f2bf(x - bf2f(xh)), yl = f2bf(y - bf2f(yh));
            const ushortT zl = f2bf(z - bf2f(zh)), sl = f2bf(sk - bf2f(sh));
            __attribute__((aligned(16))) ushortT ke[16] =
                { xh, xh, xl,  yh, yh, yl,  zh, zh, zl,
                  one, one, sh, sl, xl, yl, zl };
            ushortT* dst = Ke + ((size_t)h * Nq + n) * 16;
            ((short8*)dst)[0] = ((const short8*)ke)[0];
            ((short8*)dst)[1] = ((const short8*)ke)[1];
        }
        return;
    }

    const int mat   = blockIdx.z >> 1;
    const int chalf = blockIdx.z & 1;
    const int c0    = chalf * 8;

    const float* Wa = (mat == 0 ? Waq : (mat == 1 ? Wak : Wav)) + h * (16 * 64);
    const float* Wv = (mat == 0 ? Wvq : (mat == 1 ? Wvk : Wvv)) + h * (16 * 16);

    float axr[64];
    {
        const floatx4* p = (const floatx4*)(ax + (size_t)n * 64);
        #pragma unroll
        for (int i = 0; i < 16; i++) {
            floatx4 t = p[i];
            axr[4*i+0] = t.x; axr[4*i+1] = t.y; axr[4*i+2] = t.z; axr[4*i+3] = t.w;
        }
    }
    float vxr[48];
    {
        const floatx4* p = (const floatx4*)(vx + (size_t)n * 48);
        #pragma unroll
        for (int i = 0; i < 12; i++) {
            floatx4 t = p[i];
            vxr[4*i+0] = t.x; vxr[4*i+1] = t.y; vxr[4*i+2] = t.z; vxr[4*i+3] = t.w;
        }
    }

    float acca[8] = {};
    float accv[8][3] = {};
    #pragma unroll
    for (int d = 0; d < 64; d++) {
        #pragma unroll
        for (int cc = 0; cc < 8; cc++)
            acca[cc] = fmaf(Wa[(c0 + cc) * 64 + d], axr[d], acca[cc]);
    }
    #pragma unroll
    for (int j = 0; j < 16; j++) {
        #pragma unroll
        for (int cc = 0; cc < 8; cc++) {
            const float w = Wv[(c0 + cc) * 16 + j];
            accv[cc][0] = fmaf(w, vxr[3*j+0], accv[cc][0]);
            accv[cc][1] = fmaf(w, vxr[3*j+1], accv[cc][1]);
            accv[cc][2] = fmaf(w, vxr[3*j+2], accv[cc][2]);
        }
    }

    const float sc_extra = (mat == 0) ? LOG2E : 1.0f;
    __attribute__((aligned(16))) ushortT ob[32];
    #pragma unroll
    for (int cc = 0; cc < 8; cc++) {
        float a = acca[cc], v0 = accv[cc][0], v1 = accv[cc][1], v2 = accv[cc][2];
        float s = 1.0f;
        if (mat < 2) {
            const float nsq = a*a + v0*v0 + v1*v1 + v2*v2;
            s = rsqrtf(sqrtf(1.0f + nsq)) * sc_extra;   // (1+nsq)^(-1/4)
        }
        ob[4*cc+0] = f2bf(a  * s);
        ob[4*cc+1] = f2bf(v0 * s);
        ob[4*cc+2] = f2bf(v1 * s);
        ob[4*cc+3] = f2bf(v2 * s);
    }

    if (mat < 2) {
        ushortT* dst = (mat == 0 ? Qg : Kg) + ((size_t)(h * Nq + n)) * 64 + c0 * 4;
        #pragma unroll
        for (int i = 0; i < 4; i++) ((short8*)dst)[i] = ((const short8*)ob)[i];
    } else {
        // permuted V store: key n -> slot within its 32-key group
        const int u    = n & 31;
        const int slot = ((u >> 2) & 3) * 8 + (u >> 4) * 4 + (u & 3);
        const int np   = (n & ~31) | slot;
        #pragma unroll
        for (int cc = 0; cc < 8; cc++)
            #pragma unroll
            for (int j = 0; j < 4; j++) {
                const int d = c0 * 4 + cc * 4 + j;
                Vtg[((size_t)(h * 64 + d)) * Nq + np] = ob[4*cc+j];
            }
    }
}

// ---------------------------------------------------------------------------
// Kernel 2 (R9 structure; epilogue now stores bf16 partials): pipelined
//   transposed-S flash attention, 64 q/wave (4 qg), 4 waves/block. Logit =
//   3 MFMAs (2x QK64 + 1x ext-16, quads 2/3 zeroed). PV b128 (permuted V);
//   l via ones-MFMA (fp32); raw s_barrier/vmcnt double-buffer pipeline.
//   partO stored bf16: merge divides by fp32 l, so only ~2^-10 relative
//   noise per segment survives into the output.
// ---------------------------------------------------------------------------
__global__ __launch_bounds__(256, 2) void attn_kernel(
    const ushortT* __restrict__ Qg, const ushortT* __restrict__ Kg,
    const ushortT* __restrict__ Vtg,
    const ushortT* __restrict__ Qe, const ushortT* __restrict__ Ke,
    ushortT* __restrict__ partO, float* __restrict__ partL)
{
    __shared__ __attribute__((aligned(16))) ushortT kE[2][64 * 64];   // swizzled [key][feat]
    __shared__ __attribute__((aligned(16))) ushortT vE[2][64 * 64];   // swizzled [feat][slot]
    __shared__ __attribute__((aligned(16))) ushortT kE2[2][64 * 16];  // ext slots [key][16]

    const int tid  = threadIdx.x;
    const int w    = tid >> 6;
    const int lane = tid & 63;
    const int quad = lane >> 4;
    const int ln   = lane & 15;
    const int m7   = ln & 7;
    const int h    = blockIdx.y;
    const int seg  = blockIdx.z;
    const int qw   = blockIdx.x * 256 + w * 64;     // wave's 64 queries

    const short8 z8 = {0,0,0,0,0,0,0,0};

    // Q fragments (B-operand; Q pre-scaled by log2e) + extended Q features
    short8 qf[4][2];
    short8 qf2[4];
    #pragma unroll
    for (int qg = 0; qg < 4; qg++) {
        const size_t qi = (size_t)h*Nq + qw + qg*16 + ln;
        const short8* qp = (const short8*)(Qg + qi*64 + quad*8);
        qf[qg][0] = qp[0];
        qf[qg][1] = qp[4];
        qf2[qg] = z8;
        if (quad < 2)
            qf2[qg] = *(const short8*)(Qe + qi*16 + quad*8);
    }

    const ushortT* Khg  = Kg  + (size_t)h * Nq * 64;
    const ushortT* Vhg  = Vtg + (size_t)h * 64 * Nq;
    const ushortT* Kehg = Ke  + (size_t)h * Nq * 16;

    floatx4 O[4][4] = {};          // [qg][featgroup]: q=quad*4+r, feat=g*16+ln
    floatx4 Ol[4]   = {};          // row-sums l via ones-MFMA
    const short8 vones = {(short)0x3F80, (short)0x3F80, (short)0x3F80, (short)0x3F80,
                          (short)0x3F80, (short)0x3F80, (short)0x3F80, (short)0x3F80};

    // --- DMA stage of one 64-key tile into buffer b (block-cooperative) ---
    auto stage = [&](int k0, int b) {
        #pragma unroll
        for (int i = 0; i < 2; i++) {
            const int cbase = i * 256 + w * 64;     // wave-uniform LDS chunk base
            const int cc    = cbase + lane;         // 0..511
            const int row   = cc >> 3;
            const int part  = (cc & 7) ^ (row & 7); // XOR swizzle
            gld16(Khg + (size_t)(k0 + row)*64 + part*8, (char*)kE[b] + cbase*16);
            gld16(Vhg + (size_t)row*Nq + k0 + part*8, (char*)vE[b] + cbase*16);
        }
        // ext slots: 128 chunks of 16B, 32 per wave (lanes 0..31 active)
        if (lane < 32) {
            const int cc = w * 32 + lane;           // 0..127
            gld16(Kehg + (size_t)(k0 + (cc >> 1))*16 + (cc & 1)*8,
                  (char*)kE2[b] + w * 512);
        }
    };

    stage(seg * NKT * 64, 0);
    int buf = 0;

    #pragma unroll 1
    for (int kt = 0; kt < NKT; kt++) {
        WAIT_VM0();       // own DMA(t) complete
        BARRIER();        // all waves' DMA(t) complete; compute(t-1) done
        if (kt + 1 < NKT) stage((seg * NKT + kt + 1) * 64, buf ^ 1);  // overlaps compute(t)

        const ushortT* kb  = kE[buf];
        const ushortT* vb  = vE[buf];
        const ushortT* kb2 = kE2[buf];

        #pragma unroll
        for (int c2 = 0; c2 < 2; c2++) {
            short4T ph[2][4];      // [kk2][qg] P bf16, keys quad*4+r
            #pragma unroll
            for (int kk2 = 0; kk2 < 2; kk2++) {
                const int kk  = c2*2 + kk2;
                const int row = kk*16 + ln;
                const int p0  = quad ^ m7;
                const short8 kf0 = *(const short8*)&kb[row*64 + p0*8];
                const short8 kf1 = *(const short8*)&kb[row*64 + (p0^4)*8];
                short8 kf2 = z8;
                if (quad < 2)
                    kf2 = *(const short8*)&kb2[row*16 + quad*8];
                #pragma unroll
                for (int qg = 0; qg < 4; qg++) {
                    floatx4 S = {0.f, 0.f, 0.f, 0.f};
                    S = __builtin_amdgcn_mfma_f32_16x16x32_bf16(kf0, qf[qg][0], S, 0, 0, 0);
                    S = __builtin_amdgcn_mfma_f32_16x16x32_bf16(kf1, qf[qg][1], S, 0, 0, 0);
                    S = __builtin_amdgcn_mfma_f32_16x16x32_bf16(kf2, qf2[qg],  S, 0, 0, 0);
                    // S already includes the full distance bias (log2-domain)
                    const float p0v = __builtin_amdgcn_exp2f(S[0]);
                    const float p1v = __builtin_amdgcn_exp2f(S[1]);
                    const float p2v = __builtin_amdgcn_exp2f(S[2]);
                    const float p3v = __builtin_amdgcn_exp2f(S[3]);
                    ph[kk2][qg] = (short4T){ (short)f2bf(p0v), (short)f2bf(p1v),
                                             (short)f2bf(p2v), (short)f2bf(p3v) };
                }
            }
            // P A-frags for K=32: position quad*8+j <-> key c2*32 +
            //   (j<4 ? quad*4+j : 16+quad*4+(j-4))  == permuted-V slot order
            short8 pf[4];
            #pragma unroll
            for (int qg = 0; qg < 4; qg++)
                pf[qg] = (short8){ ph[0][qg].x, ph[0][qg].y, ph[0][qg].z, ph[0][qg].w,
                                   ph[1][qg].x, ph[1][qg].y, ph[1][qg].z, ph[1][qg].w };
            #pragma unroll
            for (int g = 0; g < 4; g++) {
                const int feat = g*16 + ln;
                const int pt   = (c2*4 + quad) ^ m7;   // permuted-V chunk, swizzled
                const short8 vf = *(const short8*)&vb[feat*64 + pt*8];
                #pragma unroll
                for (int qg = 0; qg < 4; qg++)
                    O[qg][g] = __builtin_amdgcn_mfma_f32_16x16x32_bf16(pf[qg], vf, O[qg][g], 0, 0, 0);
            }
            #pragma unroll
            for (int qg = 0; qg < 4; qg++)
                Ol[qg] = __builtin_amdgcn_mfma_f32_16x16x32_bf16(pf[qg], vones, Ol[qg], 0, 0, 0);
        }
        buf ^= 1;
    }

    const int hs = h * SEG + seg;
    #pragma unroll
    for (int qg = 0; qg < 4; qg++)
        #pragma unroll
        for (int r = 0; r < 4; r++) {
            const int q = qw + qg*16 + quad*4 + r;
            const size_t base = ((size_t)hs * Nq + q) * 64;
            #pragma unroll
            for (int g = 0; g < 4; g++)
                partO[base + g*16 + ln] = f2bf(O[qg][g][r]);   // bf16 partials
        }
    if (ln == 0) {
        #pragma unroll
        for (int qg = 0; qg < 4; qg++)
            #pragma unroll
            for (int r = 0; r < 4; r++)
                partL[(size_t)hs * Nq + qw + qg*16 + quad*4 + r] = Ol[qg][r];
    }
}

// ---------------------------------------------------------------------------
// Kernel 3 (R10 structure; reads bf16 partials): merge + normalize + project,
//   256 blocks of 16 queries (1024 waves). Merge: 4 (d,q) elems/thread,
//   coalesced in d, fp32 accumulate. Project: thread -> (q=tid&15, g=tid>>4).
//   ay = O[0:16]; vy[i][v] = O[16+3i+v].
// ---------------------------------------------------------------------------
__global__ __launch_bounds__(256) void finish_kernel(
    const ushortT* __restrict__ partO, const float* __restrict__ partL,
    const float* __restrict__ Wao, const float* __restrict__ Wvo,
    float* __restrict__ out)
{
    __shared__ float T[64 * 17];
    __shared__ float linvS[4][16];
    const int tid = threadIdx.x;
    const int q0  = blockIdx.x * 16;

    if (tid < 64) {
        const int hh = tid >> 4, qq = tid & 15;
        float s = 0.f;
        #pragma unroll
        for (int sg = 0; sg < SEG; sg++)
            s += partL[(size_t)(hh * SEG + sg) * Nq + q0 + qq];
        linvS[hh][qq] = 1.0f / (s * 64.0f);    // 1/(l*sqrt(N))
    }
    __syncthreads();

    const int qT = tid & 15;      // project-phase query (n = q0 + qT)
    const int g  = tid >> 4;      // project-phase output group 0..15
    float aacc[4] = {};
    float vacc[3] = {};

    for (int h = 0; h < 4; h++) {
        // merge phase: 1024 (d,q) elements, 4 per thread, coalesced in d
        #pragma unroll
        for (int i = 0; i < 4; i++) {
            const int idx = tid + i * 256;
            const int d = idx & 63;
            const int q = idx >> 6;
            float acc = 0.f;
            #pragma unroll
            for (int sg = 0; sg < SEG; sg++)
                acc += bf2f(partO[((size_t)(h * SEG + sg) * Nq + q0 + q) * 64 + d]);
            T[d * 17 + q] = acc * linvS[h][q];
        }
        __syncthreads();

        // project phase
        float oh[64];
        #pragma unroll
        for (int d = 0; d < 64; d++)
            oh[d] = T[d * 17 + qT];
        #pragma unroll
        for (int jj = 0; jj < 4; jj++) {
            const int j = g * 4 + jj;
            float acc = aacc[jj];
            #pragma unroll
            for (int i = 0; i < 16; i++)
                acc = fmaf(Wao[(h * 64 + j) * 16 + i], oh[i], acc);
            aacc[jj] = acc;
        }
        #pragma unroll
        for (int i = 0; i < 16; i++) {
            const float wv = Wvo[(h * 16 + g) * 16 + i];
            vacc[0] = fmaf(wv, oh[16 + 3 * i + 0], vacc[0]);
            vacc[1] = fmaf(wv, oh[16 + 3 * i + 1], vacc[1]);
            vacc[2] = fmaf(wv, oh[16 + 3 * i + 2], vacc[2]);
        }
        __syncthreads();   // T reused next h
    }

    const int n = q0 + qT;
    #pragma unroll
    for (int jj = 0; jj < 4; jj++)
        out[(size_t)n * 64 + g * 4 + jj] = aacc[jj];
    float* outv = out + (size_t)Nq * 64;
    #pragma unroll
    for (int c = 0; c < 3; c++)
        outv[((size_t)n * 16 + g) * 3 + c] = vacc[c];
}

// ---------------------------------------------------------------------------
extern "C" void kernel_launch(void* const* d_in, const int* in_sizes, int n_in,
                              void* d_out, int out_size, void* d_ws, size_t ws_size,
                              hipStream_t stream)
{
    const float* ax    = (const float*)d_in[0];
    const float* vx    = (const float*)d_in[1];
    const float* pos_k = (const float*)d_in[2];
    const float* pos_q = (const float*)d_in[3];
    const float* Waq   = (const float*)d_in[4];
    const float* Wvq   = (const float*)d_in[5];
    const float* Wak   = (const float*)d_in[6];
    const float* Wvk   = (const float*)d_in[7];
    const float* Wav   = (const float*)d_in[8];
    const float* Wvv   = (const float*)d_in[9];
    const float* Wao   = (const float*)d_in[10];
    const float* Wvo   = (const float*)d_in[11];
    float* out = (float*)d_out;

    const size_t MB = 1024 * 1024;
    char* ws = (char*)d_ws;
    // layout: Q(2MB) K(2MB) Vt(2MB) Qe(512K) Ke(512K) partO(16.8MB bf16) partL(512K)
    ushortT* Qg   = (ushortT*)(ws);
    ushortT* Kg   = (ushortT*)(ws + 2*MB);
    ushortT* Vtg  = (ushortT*)(ws + 4*MB);
    ushortT* Qe   = (ushortT*)(ws + 6*MB);
    ushortT* Ke   = (ushortT*)(ws + 6*MB + (size_t)H*Nq*16*2);
    ushortT* partO = (ushortT*)(ws + 6*MB + (size_t)2*H*Nq*16*2);
    float*   partL = (float*)((char*)partO + (size_t)H*SEG*Nq*64*2);

    qkv_kernel<<<dim3(Nq/256, H, 7), 256, 0, stream>>>(
        ax, vx, pos_q, pos_k, Waq, Wvq, Wak, Wvk, Wav, Wvv, Qg, Kg, Vtg, Qe, Ke);
    attn_kernel<<<dim3(Nq/256, H, SEG), 256, 0, stream>>>(
        Qg, Kg, Vtg, Qe, Ke, partO, partL);
    finish_kernel<<<dim3(Nq/16), 256, 0, stream>>>(partO, partL, Wao, Wvo, out);
}

// Round 12
// 120.056 us; speedup vs baseline: 1.0433x; 1.0433x over previous
//
#include <hip/hip_runtime.h>

#define H 4
#define Nq 4096
#define SEG 8
#define NKT ((Nq / SEG) / 64)
#define LOG2E 1.44269504088896340736f

typedef unsigned short ushortT;
typedef __attribute__((ext_vector_type(4))) short short4T;
typedef __attribute__((ext_vector_type(8))) short short8;
typedef __attribute__((ext_vector_type(4))) float floatx4;

// raw pipeline primitives (R4/R7/R8/R9-verified)
#define WAIT_VM0() asm volatile("s_waitcnt vmcnt(0)" ::: "memory")
#define BARRIER()  asm volatile("s_barrier" ::: "memory")

// round-half-up f32 -> bf16 (inputs finite)
static __device__ __forceinline__ ushortT f2bf(float x) {
    unsigned int u = __builtin_bit_cast(unsigned int, x);
    return (ushortT)((u + 0x8000u) >> 16);
}
static __device__ __forceinline__ float bf2f(ushortT h) {
    return __builtin_bit_cast(float, (unsigned int)h << 16);
}

// async global->LDS: PER-LANE global address -> LDS uniform base + lane*16.
static __device__ __forceinline__ void gld16(const void* g, void* l) {
    __builtin_amdgcn_global_load_lds(
        reinterpret_cast<const __attribute__((address_space(1))) unsigned int*>(
            reinterpret_cast<unsigned long long>(g)),
        reinterpret_cast<__attribute__((address_space(3))) unsigned int*>(
            static_cast<unsigned int>(reinterpret_cast<unsigned long long>(l))),
        16, 0, 0);
}

// ---------------------------------------------------------------------------
// Kernel 1 (unchanged from R9/R10): QKV projection + stack + vec-activation;
//   z==6 builds hi/lo split EXTENDED pos features (16 bf16 slots per side) so
//   attn computes the full logit (QK + distance bias, incl. log2e) in MFMA.
//   V stored PERMUTED (32-key groups, slot quad*8+hi*4+r) for b128 PV frags.
// ---------------------------------------------------------------------------
__global__ __launch_bounds__(256) void qkv_kernel(
    const float* __restrict__ ax, const float* __restrict__ vx,
    const float* __restrict__ pos_q, const float* __restrict__ pos_k,
    const float* __restrict__ Waq, const float* __restrict__ Wvq,
    const float* __restrict__ Wak, const float* __restrict__ Wvk,
    const float* __restrict__ Wav, const float* __restrict__ Wvv,
    ushortT* __restrict__ Qg, ushortT* __restrict__ Kg, ushortT* __restrict__ Vtg,
    ushortT* __restrict__ Qe, ushortT* __restrict__ Ke)
{
    const int h = blockIdx.y;
    const int n = blockIdx.x * 256 + threadIdx.x;

    if (blockIdx.z == 6) {      // extended pos-feature branch (block-uniform)
        const float c = LOG2E / (float)(1 << (2 * h));
        const ushortT one = 0x3F80;
        {   // Q side
            const float* p = pos_q + ((size_t)h * Nq + n) * 3;
            const float x = 2.f*c*p[0], y = 2.f*c*p[1], z = 2.f*c*p[2];
            const float wq = -c * (p[0]*p[0] + p[1]*p[1] + p[2]*p[2]);
            const ushortT xh = f2bf(x), yh = f2bf(y), zh = f2bf(z), wh = f2bf(wq);
            const ushortT xl = f2bf(x - bf2f(xh)), yl = f2bf(y - bf2f(yh));
            const ushortT zl = f2bf(z - bf2f(zh)), wl = f2bf(wq - bf2f(wh));
            __attribute__((aligned(16))) ushortT qe[16] =
                { xh, xl, xh,  yh, yl, yh,  zh, zl, zh,
                  wh, wl, one, one, xl, yl, zl };
            ushortT* dst = Qe + ((size_t)h * Nq + n) * 16;
            ((short8*)dst)[0] = ((const short8*)qe)[0];
            ((short8*)dst)[1] = ((const short8*)qe)[1];
        }
        {   // K side
            const float* p = pos_k + ((size_t)h * Nq + n) * 3;
            const float x = p[0], y = p[1], z = p[2];
            const float sk = -c * (x*x + y*y + z*z);
            const ushortT xh = f2bf(x), yh = f2bf(y), zh = f2bf(z), sh = f2bf(sk);
            const ushortT xl = f2bf(x - bf2f(xh)), yl = f2bf(y - bf2f(yh));
            const ushortT zl = f2bf(z - bf2f(zh)), sl = f2bf(sk - bf2f(sh));
            __attribute__((aligned(16))) ushortT ke[16] =
                { xh, xh, xl,  yh, yh, yl,  zh, zh, zl,
                  one, one, sh, sl, xl, yl, zl };
            ushortT* dst = Ke + ((size_t)h * Nq + n) * 16;
            ((short8*)dst)[0] = ((const short8*)ke)[0];
            ((short8*)dst)[1] = ((const short8*)ke)[1];
        }
        return;
    }

    const int mat   = blockIdx.z >> 1;
    const int chalf = blockIdx.z & 1;
    const int c0    = chalf * 8;

    const float* Wa = (mat == 0 ? Waq : (mat == 1 ? Wak : Wav)) + h * (16 * 64);
    const float* Wv = (mat == 0 ? Wvq : (mat == 1 ? Wvk : Wvv)) + h * (16 * 16);

    float axr[64];
    {
        const floatx4* p = (const floatx4*)(ax + (size_t)n * 64);
        #pragma unroll
        for (int i = 0; i < 16; i++) {
            floatx4 t = p[i];
            axr[4*i+0] = t.x; axr[4*i+1] = t.y; axr[4*i+2] = t.z; axr[4*i+3] = t.w;
        }
    }
    float vxr[48];
    {
        const floatx4* p = (const floatx4*)(vx + (size_t)n * 48);
        #pragma unroll
        for (int i = 0; i < 12; i++) {
            floatx4 t = p[i];
            vxr[4*i+0] = t.x; vxr[4*i+1] = t.y; vxr[4*i+2] = t.z; vxr[4*i+3] = t.w;
        }
    }

    float acca[8] = {};
    float accv[8][3] = {};
    #pragma unroll
    for (int d = 0; d < 64; d++) {
        #pragma unroll
        for (int cc = 0; cc < 8; cc++)
            acca[cc] = fmaf(Wa[(c0 + cc) * 64 + d], axr[d], acca[cc]);
    }
    #pragma unroll
    for (int j = 0; j < 16; j++) {
        #pragma unroll
        for (int cc = 0; cc < 8; cc++) {
            const float w = Wv[(c0 + cc) * 16 + j];
            accv[cc][0] = fmaf(w, vxr[3*j+0], accv[cc][0]);
            accv[cc][1] = fmaf(w, vxr[3*j+1], accv[cc][1]);
            accv[cc][2] = fmaf(w, vxr[3*j+2], accv[cc][2]);
        }
    }

    const float sc_extra = (mat == 0) ? LOG2E : 1.0f;
    __attribute__((aligned(16))) ushortT ob[32];
    #pragma unroll
    for (int cc = 0; cc < 8; cc++) {
        float a = acca[cc], v0 = accv[cc][0], v1 = accv[cc][1], v2 = accv[cc][2];
        float s = 1.0f;
        if (mat < 2) {
            const float nsq = a*a + v0*v0 + v1*v1 + v2*v2;
            s = rsqrtf(sqrtf(1.0f + nsq)) * sc_extra;   // (1+nsq)^(-1/4)
        }
        ob[4*cc+0] = f2bf(a  * s);
        ob[4*cc+1] = f2bf(v0 * s);
        ob[4*cc+2] = f2bf(v1 * s);
        ob[4*cc+3] = f2bf(v2 * s);
    }

    if (mat < 2) {
        ushortT* dst = (mat == 0 ? Qg : Kg) + ((size_t)(h * Nq + n)) * 64 + c0 * 4;
        #pragma unroll
        for (int i = 0; i < 4; i++) ((short8*)dst)[i] = ((const short8*)ob)[i];
    } else {
        // permuted V store: key n -> slot within its 32-key group
        const int u    = n & 31;
        const int slot = ((u >> 2) & 3) * 8 + (u >> 4) * 4 + (u & 3);
        const int np   = (n & ~31) | slot;
        #pragma unroll
        for (int cc = 0; cc < 8; cc++)
            #pragma unroll
            for (int j = 0; j < 4; j++) {
                const int d = c0 * 4 + cc * 4 + j;
                Vtg[((size_t)(h * 64 + d)) * Nq + np] = ob[4*cc+j];
            }
    }
}

// ---------------------------------------------------------------------------
// Kernel 2 (unchanged from R9/R10, fp32 partials): pipelined transposed-S
//   flash attention, 64 q/wave (4 qg), 4 waves/block, one staged 64-key tile.
//   Logit = 3 MFMAs (2x QK64 + 1x ext-16, quads 2/3 zeroed). PV b128
//   (permuted V); l via ones-MFMA; raw s_barrier/vmcnt double-buffer pipeline.
// ---------------------------------------------------------------------------
__global__ __launch_bounds__(256, 2) void attn_kernel(
    const ushortT* __restrict__ Qg, const ushortT* __restrict__ Kg,
    const ushortT* __restrict__ Vtg,
    const ushortT* __restrict__ Qe, const ushortT* __restrict__ Ke,
    float* __restrict__ partO, float* __restrict__ partL)
{
    __shared__ __attribute__((aligned(16))) ushortT kE[2][64 * 64];   // swizzled [key][feat]
    __shared__ __attribute__((aligned(16))) ushortT vE[2][64 * 64];   // swizzled [feat][slot]
    __shared__ __attribute__((aligned(16))) ushortT kE2[2][64 * 16];  // ext slots [key][16]

    const int tid  = threadIdx.x;
    const int w    = tid >> 6;
    const int lane = tid & 63;
    const int quad = lane >> 4;
    const int ln   = lane & 15;
    const int m7   = ln & 7;
    const int h    = blockIdx.y;
    const int seg  = blockIdx.z;
    const int qw   = blockIdx.x * 256 + w * 64;     // wave's 64 queries

    const short8 z8 = {0,0,0,0,0,0,0,0};

    // Q fragments (B-operand; Q pre-scaled by log2e) + extended Q features
    short8 qf[4][2];
    short8 qf2[4];
    #pragma unroll
    for (int qg = 0; qg < 4; qg++) {
        const size_t qi = (size_t)h*Nq + qw + qg*16 + ln;
        const short8* qp = (const short8*)(Qg + qi*64 + quad*8);
        qf[qg][0] = qp[0];
        qf[qg][1] = qp[4];
        qf2[qg] = z8;
        if (quad < 2)
            qf2[qg] = *(const short8*)(Qe + qi*16 + quad*8);
    }

    const ushortT* Khg  = Kg  + (size_t)h * Nq * 64;
    const ushortT* Vhg  = Vtg + (size_t)h * 64 * Nq;
    const ushortT* Kehg = Ke  + (size_t)h * Nq * 16;

    floatx4 O[4][4] = {};          // [qg][featgroup]: q=quad*4+r, feat=g*16+ln
    floatx4 Ol[4]   = {};          // row-sums l via ones-MFMA
    const short8 vones = {(short)0x3F80, (short)0x3F80, (short)0x3F80, (short)0x3F80,
                          (short)0x3F80, (short)0x3F80, (short)0x3F80, (short)0x3F80};

    // --- DMA stage of one 64-key tile into buffer b (block-cooperative) ---
    auto stage = [&](int k0, int b) {
        #pragma unroll
        for (int i = 0; i < 2; i++) {
            const int cbase = i * 256 + w * 64;     // wave-uniform LDS chunk base
            const int cc    = cbase + lane;         // 0..511
            const int row   = cc >> 3;
            const int part  = (cc & 7) ^ (row & 7); // XOR swizzle
            gld16(Khg + (size_t)(k0 + row)*64 + part*8, (char*)kE[b] + cbase*16);
            gld16(Vhg + (size_t)row*Nq + k0 + part*8, (char*)vE[b] + cbase*16);
        }
        // ext slots: 128 chunks of 16B, 32 per wave (lanes 0..31 active)
        if (lane < 32) {
            const int cc = w * 32 + lane;           // 0..127
            gld16(Kehg + (size_t)(k0 + (cc >> 1))*16 + (cc & 1)*8,
                  (char*)kE2[b] + w * 512);
        }
    };

    stage(seg * NKT * 64, 0);
    int buf = 0;

    #pragma unroll 1
    for (int kt = 0; kt < NKT; kt++) {
        WAIT_VM0();       // own DMA(t) complete
        BARRIER();        // all waves' DMA(t) complete; compute(t-1) done
        if (kt + 1 < NKT) stage((seg * NKT + kt + 1) * 64, buf ^ 1);  // overlaps compute(t)

        const ushortT* kb  = kE[buf];
        const ushortT* vb  = vE[buf];
        const ushortT* kb2 = kE2[buf];

        #pragma unroll
        for (int c2 = 0; c2 < 2; c2++) {
            short4T ph[2][4];      // [kk2][qg] P bf16, keys quad*4+r
            #pragma unroll
            for (int kk2 = 0; kk2 < 2; kk2++) {
                const int kk  = c2*2 + kk2;
                const int row = kk*16 + ln;
                const int p0  = quad ^ m7;
                const short8 kf0 = *(const short8*)&kb[row*64 + p0*8];
                const short8 kf1 = *(const short8*)&kb[row*64 + (p0^4)*8];
                short8 kf2 = z8;
                if (quad < 2)
                    kf2 = *(const short8*)&kb2[row*16 + quad*8];
                #pragma unroll
                for (int qg = 0; qg < 4; qg++) {
                    floatx4 S = {0.f, 0.f, 0.f, 0.f};
                    S = __builtin_amdgcn_mfma_f32_16x16x32_bf16(kf0, qf[qg][0], S, 0, 0, 0);
                    S = __builtin_amdgcn_mfma_f32_16x16x32_bf16(kf1, qf[qg][1], S, 0, 0, 0);
                    S = __builtin_amdgcn_mfma_f32_16x16x32_bf16(kf2, qf2[qg],  S, 0, 0, 0);
                    // S already includes the full distance bias (log2-domain)
                    const float p0v = __builtin_amdgcn_exp2f(S[0]);
                    const float p1v = __builtin_amdgcn_exp2f(S[1]);
                    const float p2v = __builtin_amdgcn_exp2f(S[2]);
                    const float p3v = __builtin_amdgcn_exp2f(S[3]);
                    ph[kk2][qg] = (short4T){ (short)f2bf(p0v), (short)f2bf(p1v),
                                             (short)f2bf(p2v), (short)f2bf(p3v) };
                }
            }
            // P A-frags for K=32: position quad*8+j <-> key c2*32 +
            //   (j<4 ? quad*4+j : 16+quad*4+(j-4))  == permuted-V slot order
            short8 pf[4];
            #pragma unroll
            for (int qg = 0; qg < 4; qg++)
                pf[qg] = (short8){ ph[0][qg].x, ph[0][qg].y, ph[0][qg].z, ph[0][qg].w,
                                   ph[1][qg].x, ph[1][qg].y, ph[1][qg].z, ph[1][qg].w };
            #pragma unroll
            for (int g = 0; g < 4; g++) {
                const int feat = g*16 + ln;
                const int pt   = (c2*4 + quad) ^ m7;   // permuted-V chunk, swizzled
                const short8 vf = *(const short8*)&vb[feat*64 + pt*8];
                #pragma unroll
                for (int qg = 0; qg < 4; qg++)
                    O[qg][g] = __builtin_amdgcn_mfma_f32_16x16x32_bf16(pf[qg], vf, O[qg][g], 0, 0, 0);
            }
            #pragma unroll
            for (int qg = 0; qg < 4; qg++)
                Ol[qg] = __builtin_amdgcn_mfma_f32_16x16x32_bf16(pf[qg], vones, Ol[qg], 0, 0, 0);
        }
        buf ^= 1;
    }

    const int hs = h * SEG + seg;
    #pragma unroll
    for (int qg = 0; qg < 4; qg++)
        #pragma unroll
        for (int r = 0; r < 4; r++) {
            const int q = qw + qg*16 + quad*4 + r;
            const size_t base = ((size_t)hs * Nq + q) * 64;
            #pragma unroll
            for (int g = 0; g < 4; g++)
                partO[base + g*16 + ln] = O[qg][g][r];
        }
    if (ln == 0) {
        #pragma unroll
        for (int qg = 0; qg < 4; qg++)
            #pragma unroll
            for (int r = 0; r < 4; r++)
                partL[(size_t)hs * Nq + qw + qg*16 + quad*4 + r] = Ol[qg][r];
    }
}

// ---------------------------------------------------------------------------
// Kernel 3 (v12): merge + normalize + project, 256 blocks of 16 queries
//   (1024 waves). Merge now VECTORIZED: one float4 (d-group) per thread per
//   segment -> 8 dwordx4 loads/thread instead of 32 dword. Project: thread ->
//   (q = tid&15, group g = tid>>4). ay = O[0:16]; vy[i][v] = O[16+3i+v].
// ---------------------------------------------------------------------------
__global__ __launch_bounds__(256) void finish_kernel(
    const float* __restrict__ partO, const float* __restrict__ partL,
    const float* __restrict__ Wao, const float* __restrict__ Wvo,
    float* __restrict__ out)
{
    __shared__ float T[64 * 17];
    __shared__ float linvS[4][16];
    const int tid = threadIdx.x;
    const int q0  = blockIdx.x * 16;

    if (tid < 64) {
        const int hh = tid >> 4, qq = tid & 15;
        float s = 0.f;
        #pragma unroll
        for (int sg = 0; sg < SEG; sg++)
            s += partL[(size_t)(hh * SEG + sg) * Nq + q0 + qq];
        linvS[hh][qq] = 1.0f / (s * 64.0f);    // 1/(l*sqrt(N))
    }
    __syncthreads();

    const int qT = tid & 15;      // project-phase query (n = q0 + qT)
    const int g  = tid >> 4;      // project-phase output group 0..15
    const int dg = (tid & 15) * 4;// merge-phase d-group (16B aligned)
    const int qM = tid >> 4;      // merge-phase query
    float aacc[4] = {};
    float vacc[3] = {};

    for (int h = 0; h < 4; h++) {
        // merge phase: 1024 (d,q) elements, one float4 per thread;
        // 16 lanes x 16B = 256B contiguous per q-row (fully coalesced)
        {
            floatx4 acc = {0.f, 0.f, 0.f, 0.f};
            #pragma unroll
            for (int sg = 0; sg < SEG; sg++)
                acc += *(const floatx4*)&partO[((size_t)(h * SEG + sg) * Nq + q0 + qM) * 64 + dg];
            const float li = linvS[h][qM];
            #pragma unroll
            for (int j = 0; j < 4; j++)
                T[(dg + j) * 17 + qM] = acc[j] * li;
        }
        __syncthreads();

        // project phase
        float oh[64];
        #pragma unroll
        for (int d = 0; d < 64; d++)
            oh[d] = T[d * 17 + qT];
        #pragma unroll
        for (int jj = 0; jj < 4; jj++) {
            const int j = g * 4 + jj;
            float acc = aacc[jj];
            #pragma unroll
            for (int i = 0; i < 16; i++)
                acc = fmaf(Wao[(h * 64 + j) * 16 + i], oh[i], acc);
            aacc[jj] = acc;
        }
        #pragma unroll
        for (int i = 0; i < 16; i++) {
            const float wv = Wvo[(h * 16 + g) * 16 + i];
            vacc[0] = fmaf(wv, oh[16 + 3 * i + 0], vacc[0]);
            vacc[1] = fmaf(wv, oh[16 + 3 * i + 1], vacc[1]);
            vacc[2] = fmaf(wv, oh[16 + 3 * i + 2], vacc[2]);
        }
        __syncthreads();   // T reused next h
    }

    const int n = q0 + qT;
    #pragma unroll
    for (int jj = 0; jj < 4; jj++)
        out[(size_t)n * 64 + g * 4 + jj] = aacc[jj];
    float* outv = out + (size_t)Nq * 64;
    #pragma unroll
    for (int c = 0; c < 3; c++)
        outv[((size_t)n * 16 + g) * 3 + c] = vacc[c];
}

// ---------------------------------------------------------------------------
extern "C" void kernel_launch(void* const* d_in, const int* in_sizes, int n_in,
                              void* d_out, int out_size, void* d_ws, size_t ws_size,
                              hipStream_t stream)
{
    const float* ax    = (const float*)d_in[0];
    const float* vx    = (const float*)d_in[1];
    const float* pos_k = (const float*)d_in[2];
    const float* pos_q = (const float*)d_in[3];
    const float* Waq   = (const float*)d_in[4];
    const float* Wvq   = (const float*)d_in[5];
    const float* Wak   = (const float*)d_in[6];
    const float* Wvk   = (const float*)d_in[7];
    const float* Wav   = (const float*)d_in[8];
    const float* Wvv   = (const float*)d_in[9];
    const float* Wao   = (const float*)d_in[10];
    const float* Wvo   = (const float*)d_in[11];
    float* out = (float*)d_out;

    const size_t MB = 1024 * 1024;
    char* ws = (char*)d_ws;
    // layout: Q(2MB) K(2MB) Vt(2MB) Qe(512K) Ke(512K) partO(33.6MB fp32) partL(512K)
    ushortT* Qg   = (ushortT*)(ws);
    ushortT* Kg   = (ushortT*)(ws + 2*MB);
    ushortT* Vtg  = (ushortT*)(ws + 4*MB);
    ushortT* Qe   = (ushortT*)(ws + 6*MB);
    ushortT* Ke   = (ushortT*)(ws + 6*MB + (size_t)H*Nq*16*2);
    float*  partO = (float*)(ws + 6*MB + (size_t)2*H*Nq*16*2);
    float*  partL = (float*)((char*)partO + (size_t)H*SEG*Nq*64*4);

    qkv_kernel<<<dim3(Nq/256, H, 7), 256, 0, stream>>>(
        ax, vx, pos_q, pos_k, Waq, Wvq, Wak, Wvk, Wav, Wvv, Qg, Kg, Vtg, Qe, Ke);
    attn_kernel<<<dim3(Nq/256, H, SEG), 256, 0, stream>>>(
        Qg, Kg, Vtg, Qe, Ke, partO, partL);
    finish_kernel<<<dim3(Nq/16), 256, 0, stream>>>(partO, partL, Wao, Wvo, out);
}